// Round 8
// baseline (241.451 us; speedup 1.0000x reference)
//
#include <hip/hip_runtime.h>
#include <math.h>

#define B_   4
#define NQ_  300
#define DIM_ 256
#define H_   8
#define HD_  32
#define N_   4096
#define QT_  19           // ceil(300/16) q-tiles per (b,h)

typedef _Float16 f16;
typedef f16   f16x8 __attribute__((ext_vector_type(8)));
typedef f16   f16x4 __attribute__((ext_vector_type(4)));
typedef float f32x4 __attribute__((ext_vector_type(4)));

#define L2E 1.44269504f

// ---------------------------------------------------------------------------
// Prep: z<4 -> WT[z][n][k] = W_z[k][n] * (z==0 ? qscale : 1), f16.
//       z==4 -> maskf[b][n] = -100*log2e*mask[b][n], f32.
// ---------------------------------------------------------------------------
__global__ __launch_bounds__(256) void prep_wt(
    const float* __restrict__ Wq, const float* __restrict__ Wk,
    const float* __restrict__ Wv, const float* __restrict__ Wp,
    const int* __restrict__ mask, f16* __restrict__ WT,
    float* __restrict__ maskf, float qscale)
{
  const int z = blockIdx.z;
  if (z == 4) {
    const int flat = blockIdx.y * 4 + blockIdx.x;
    const int idx = flat * 1024 + threadIdx.x * 4;
    int4 mm = *(const int4*)(mask + idx);
    float4 o;
    o.x = -100.f * L2E * (float)mm.x;
    o.y = -100.f * L2E * (float)mm.y;
    o.z = -100.f * L2E * (float)mm.z;
    o.w = -100.f * L2E * (float)mm.w;
    *(float4*)(maskf + idx) = o;
    return;
  }
  __shared__ float t[64][65];
  const float* W = z == 0 ? Wq : z == 1 ? Wk : z == 2 ? Wv : Wp;
  const float s = z == 0 ? qscale : 1.0f;
  f16* O = WT + (size_t)z * 65536;
  const int k0 = blockIdx.y * 64, n0 = blockIdx.x * 64;
  const int r = threadIdx.x >> 2, c0 = (threadIdx.x & 3) * 16;
#pragma unroll
  for (int c = 0; c < 16; c += 4) {
    float4 v = *(const float4*)(W + (size_t)(k0 + r) * 256 + n0 + c0 + c);
    t[r][c0 + c] = v.x; t[r][c0 + c + 1] = v.y;
    t[r][c0 + c + 2] = v.z; t[r][c0 + c + 3] = v.w;
  }
  __syncthreads();
  f16* orow = O + (size_t)(n0 + r) * 256 + k0 + c0;
#pragma unroll
  for (int c = 0; c < 16; c += 4) {
    f16x4 p;
    p[0] = (f16)(t[c0 + c + 0][r] * s);
    p[1] = (f16)(t[c0 + c + 1][r] * s);
    p[2] = (f16)(t[c0 + c + 2][r] * s);
    p[3] = (f16)(t[c0 + c + 3][r] * s);
    *(f16x4*)(orow + c) = p;
  }
}

// ---------------------------------------------------------------------------
// MFMA GEMM body: C = A @ (WT^T) + bias*scale.  WT is [n][k] f16.
// mode 0: fp32 row-major out; 1: f16 row-major;
// mode 2: f16 [b][c=n][nk=m&4095] via LDS transpose (coalesced 32B stores).
// ---------------------------------------------------------------------------
__device__ __forceinline__ void gemm_body(
    const void* __restrict__ Ain, const f16* __restrict__ WT,
    const float* __restrict__ bias, void* __restrict__ C,
    int M, float scale, int a_f16, int mode, int bm, int bn, int tid)
{
  __shared__ f16 As[64][40];
  __shared__ f16 Bs[64][40];
  __shared__ f16 Ts[64][72];
  const int lane = tid & 63;
  const int wv = tid >> 6;
  const int l15 = lane & 15, g = lane >> 4;
  const int arow = tid >> 2, akq = (tid & 3) * 8;

  f32x4 acc[4];
#pragma unroll
  for (int nt = 0; nt < 4; ++nt) acc[nt] = (f32x4){0.f, 0.f, 0.f, 0.f};

  for (int k0 = 0; k0 < 256; k0 += 32) {
    {
      const int gm = bm + arow;
      f16x8 av;
      if (gm < M) {
        if (a_f16) {
          av = *(const f16x8*)((const f16*)Ain + (size_t)gm * 256 + k0 + akq);
        } else {
          const float* ap = (const float*)Ain + (size_t)gm * 256 + k0 + akq;
          float4 a0 = *(const float4*)ap;
          float4 a1 = *(const float4*)(ap + 4);
          av[0] = (f16)a0.x; av[1] = (f16)a0.y; av[2] = (f16)a0.z; av[3] = (f16)a0.w;
          av[4] = (f16)a1.x; av[5] = (f16)a1.y; av[6] = (f16)a1.z; av[7] = (f16)a1.w;
        }
      } else {
#pragma unroll
        for (int i = 0; i < 8; ++i) av[i] = (f16)0.f;
      }
      *(f16x8*)&As[arow][akq] = av;
      *(f16x8*)&Bs[arow][akq] =
          *(const f16x8*)(WT + (size_t)(bn + arow) * 256 + k0 + akq);
    }
    __syncthreads();
    const f16x8 af = *(const f16x8*)&As[wv * 16 + l15][g * 8];
#pragma unroll
    for (int nt = 0; nt < 4; ++nt) {
      const f16x8 bf = *(const f16x8*)&Bs[nt * 16 + l15][g * 8];
      acc[nt] = __builtin_amdgcn_mfma_f32_16x16x32_f16(af, bf, acc[nt], 0, 0, 0);
    }
    __syncthreads();
  }

  if (mode == 2) {
#pragma unroll
    for (int nt = 0; nt < 4; ++nt) {
      const float bv = bias[bn + nt * 16 + l15];
#pragma unroll
      for (int r = 0; r < 4; ++r)
        Ts[nt * 16 + l15][wv * 16 + g * 4 + r] = (f16)(acc[nt][r] + bv);
    }
    __syncthreads();
    const int nl = tid >> 2, mc = (tid & 3) * 16;
    const int bb = bm >> 12, nk0 = bm & 4095;
    f16* dst = (f16*)C + (size_t)bb * (256 * 4096) +
               (size_t)(bn + nl) * 4096 + nk0 + mc;
    *(f16x8*)dst = *(const f16x8*)&Ts[nl][mc];
    *(f16x8*)(dst + 8) = *(const f16x8*)&Ts[nl][mc + 8];
  } else {
#pragma unroll
    for (int nt = 0; nt < 4; ++nt) {
      const int n = bn + nt * 16 + l15;
      const float bv = bias[n] * scale;
#pragma unroll
      for (int r = 0; r < 4; ++r) {
        const int m = bm + wv * 16 + g * 4 + r;
        if (m >= M) continue;
        const float v = acc[nt][r] + bv;
        if (mode == 0) ((float*)C)[(size_t)m * 256 + n] = v;
        else           ((f16*)C)[(size_t)m * 256 + n] = (f16)v;
      }
    }
  }
}

// z=0: Q (M=1200), z=1: K, z=2: V  — one launch for all three projections.
__global__ __launch_bounds__(256) void proj_qkv(
    const float* __restrict__ query, const float* __restrict__ kin,
    const float* __restrict__ vin, const f16* __restrict__ WT,
    const float* __restrict__ bq, const float* __restrict__ bk,
    const float* __restrict__ bv, f16* __restrict__ Qf,
    f16* __restrict__ Kf, f16* __restrict__ Vtf, float qscale)
{
  const int z = blockIdx.z;
  const int bm = blockIdx.y * 64, bn = blockIdx.x * 64;
  if (z == 0) {
    if (bm >= B_ * NQ_) return;
    gemm_body(query, WT, bq, Qf, B_ * NQ_, qscale, 0, 1, bm, bn, threadIdx.x);
  } else if (z == 1) {
    gemm_body(kin, WT + 65536, bk, Kf, B_ * N_, 1.0f, 0, 1, bm, bn, threadIdx.x);
  } else {
    gemm_body(vin, WT + 2 * 65536, bv, Vtf, B_ * N_, 1.0f, 0, 2, bm, bn, threadIdx.x);
  }
}

__global__ __launch_bounds__(256) void gemm_out(
    const f16* __restrict__ X, const f16* __restrict__ WT,
    const float* __restrict__ bp, float* __restrict__ out)
{
  gemm_body(X, WT + 3 * 65536, bp, out, B_ * NQ_, 1.0f, 1, 0,
            blockIdx.y * 64, blockIdx.x * 64, threadIdx.x);
}

// ---------------------------------------------------------------------------
// RPE MLP, fp32 (rpe ~±1500; must not round). Output transposed to
// [b][h][q][j], pre-scaled by log2e, for coalesced float4 staging in attn.
// ---------------------------------------------------------------------------
__global__ __launch_bounds__(256) void rpe_kernel(
    const float* __restrict__ refpts,
    const float* __restrict__ W1x, const float* __restrict__ b1x, const float* __restrict__ W2x,
    const float* __restrict__ W1y, const float* __restrict__ b1y, const float* __restrict__ W2y,
    float* __restrict__ rpxT, float* __restrict__ rpyT)
{
  __shared__ float sRed[4][64][9];
  const int tid = threadIdx.x;
  const int lane = tid & 63;
  const int wv = __builtin_amdgcn_readfirstlane(tid >> 6);
  const int bq = blockIdx.x;
  const int axis = blockIdx.y;
  const float* W1 = axis ? W1y : W1x;
  const float* b1 = axis ? b1y : b1x;
  const float* W2 = axis ? W2y : W2x;
  float* out = axis ? rpyT : rpxT;
  const int b = bq / NQ_, q = bq % NQ_;

  const float c  = refpts[bq * 4 + axis];
  const float sz = refpts[bq * 4 + 2 + axis];
  const float pos = (lane + 0.5f) * 16.0f;
  const float d0 = c - 0.5f * sz - pos;
  const float d1 = c + 0.5f * sz - pos;
  float acc[8] = {};
  const int r0 = wv * 128;
#pragma unroll 4
  for (int i = 0; i < 128; ++i) {
    const int r = r0 + i;
    const float w10 = W1[r], w11 = W1[512 + r], bb = b1[r];
    const float hv = fmaxf(fmaf(d0, w10, fmaf(d1, w11, bb)), 0.0f);
    const float* w2r = W2 + r * 8;
#pragma unroll
    for (int hh = 0; hh < 8; ++hh) acc[hh] += hv * w2r[hh];
  }
#pragma unroll
  for (int hh = 0; hh < 8; ++hh) sRed[wv][lane][hh] = acc[hh];
  __syncthreads();
  for (int idx = tid; idx < 512; idx += 256) {
    const int hh = idx >> 6, jj = idx & 63;
    out[((size_t)(b * H_ + hh) * NQ_ + q) * 64 + jj] =
        (sRed[0][jj][hh] + sRed[1][jj][hh] + sRed[2][jj][hh] + sRed[3][jj][hh]) * L2E;
  }
}

// ---------------------------------------------------------------------------
// MFMA attention, exact online softmax (log2 domain).
// Block = (b,h,16q), 8 waves x 512 keys, grid 608 (balance: 2.375 blocks/CU).
// Per 64-key sub-pass: batch-load 4 K-chunks + 8 V-frags + 4 mask-float4,
// 4 QK MFMA + fixup, one cross-lane max/rescale, exp2 + 8 PV MFMA.
// Partials merged via f16x4 LDS (small). LDS ~18 KB; VGPR capped at 128.
// ---------------------------------------------------------------------------
__global__ __launch_bounds__(512, 4) void attn_mfma(
    const f16* __restrict__ Qf, const f16* __restrict__ Kf,
    const f16* __restrict__ Vtf, const float* __restrict__ rpxT,
    const float* __restrict__ rpyT, const float* __restrict__ maskf,
    f16* __restrict__ X)
{
  __shared__ float srx[16][68];
  __shared__ float sry[16][68];
  __shared__ f16x4 mO4[7][2][64];
  __shared__ float mlm[7][16];
  __shared__ float mll[7][16];

  const int tid = threadIdx.x;
  const int lane = tid & 63;
  const int kh = tid >> 6;
  const int qb = blockIdx.x % QT_;
  const int h  = (blockIdx.x / QT_) % H_;
  const int b  = blockIdx.x / (QT_ * H_);
  const int q0 = qb * 16;

  {
    const int t = tid & 255;
    const int qq = t >> 4, j4 = t & 15;
    int qg = q0 + qq; if (qg > NQ_ - 1) qg = NQ_ - 1;
    const float* src = (tid < 256 ? rpxT : rpyT) +
        ((size_t)((b * H_ + h) * NQ_ + qg)) * 64 + j4 * 4;
    float4 v = *(const float4*)src;
    float* dst = (tid < 256) ? &srx[qq][j4 * 4] : &sry[qq][j4 * 4];
    *(float4*)dst = v;
  }
  __syncthreads();

  const int l15 = lane & 15, g = lane >> 4;
  const int qrow = q0 + l15;
  const int qc = qrow > NQ_ - 1 ? NQ_ - 1 : qrow;
  const f16x8 qf = *(const f16x8*)(Qf + (size_t)(b * NQ_ + qc) * 256 + h * 32 + g * 8);

  f32x4 O0 = {0.f, 0.f, 0.f, 0.f}, O1 = {0.f, 0.f, 0.f, 0.f};
  float lacc = 0.f, mrun = -1e30f;
  const f16* kb  = Kf + (size_t)b * N_ * 256 + h * 32 + g * 8;
  const f16* v0p = Vtf + (size_t)(b * 256 + h * 32 + l15) * N_ + g * 4;
  const f16* v1p = v0p + (size_t)16 * N_;
  const float* mb = maskf + b * N_;

  for (int sp = 0; sp < 8; ++sp) {
    const int kbase = kh * 512 + sp * 64;
    // ---- batched loads: 16 VMEM in flight ----
    f16x8 kf[4]; f16x4 va[4], vb[4]; float4 m4[4];
#pragma unroll
    for (int cc = 0; cc < 4; ++cc) {
      kf[cc] = *(const f16x8*)(kb + (size_t)(kbase + cc * 16 + l15) * 256);
      va[cc] = *(const f16x4*)(v0p + kbase + cc * 16);
      vb[cc] = *(const f16x4*)(v1p + kbase + cc * 16);
      m4[cc] = *(const float4*)(mb + kbase + cc * 16 + g * 4);
    }
    const float ryc = sry[l15][kbase >> 6];
    f32x4 s[4];
    float lm = -1e30f;
#pragma unroll
    for (int cc = 0; cc < 4; ++cc) {
      f32x4 S = __builtin_amdgcn_mfma_f32_16x16x32_f16(
          kf[cc], qf, (f32x4){0.f, 0.f, 0.f, 0.f}, 0, 0, 0);
      const float4 rx = *(const float4*)&srx[l15][cc * 16 + g * 4];
      s[cc][0] = fmaf(S[0], L2E, rx.x + m4[cc].x + ryc);
      s[cc][1] = fmaf(S[1], L2E, rx.y + m4[cc].y + ryc);
      s[cc][2] = fmaf(S[2], L2E, rx.z + m4[cc].z + ryc);
      s[cc][3] = fmaf(S[3], L2E, rx.w + m4[cc].w + ryc);
      lm = fmaxf(lm, fmaxf(fmaxf(s[cc][0], s[cc][1]), fmaxf(s[cc][2], s[cc][3])));
    }
    lm = fmaxf(lm, __shfl_xor(lm, 16));
    lm = fmaxf(lm, __shfl_xor(lm, 32));
    const float mn = fmaxf(mrun, lm);
    const float fr = exp2f(mrun - mn);
    mrun = mn;
    lacc *= fr;
#pragma unroll
    for (int r = 0; r < 4; ++r) { O0[r] *= fr; O1[r] *= fr; }
#pragma unroll
    for (int cc = 0; cc < 4; ++cc) {
      f16x4 pf;
#pragma unroll
      for (int r = 0; r < 4; ++r) {
        const float p = exp2f(s[cc][r] - mrun);
        lacc += p;
        pf[r] = (f16)p;
      }
      O0 = __builtin_amdgcn_mfma_f32_16x16x16f16(va[cc], pf, O0, 0, 0, 0);
      O1 = __builtin_amdgcn_mfma_f32_16x16x16f16(vb[cc], pf, O1, 0, 0, 0);
    }
  }
  lacc += __shfl_xor(lacc, 16);
  lacc += __shfl_xor(lacc, 32);

  if (kh > 0) {
    f16x4 pa, pb;
#pragma unroll
    for (int r = 0; r < 4; ++r) { pa[r] = (f16)O0[r]; pb[r] = (f16)O1[r]; }
    mO4[kh - 1][0][lane] = pa;
    mO4[kh - 1][1][lane] = pb;
    if (lane < 16) { mlm[kh - 1][lane] = mrun; mll[kh - 1][lane] = lacc; }
  }
  __syncthreads();
  if (kh == 0) {
    float ms = mrun;
#pragma unroll
    for (int w = 0; w < 7; ++w) ms = fmaxf(ms, mlm[w][l15]);
    const float f0 = exp2f(mrun - ms);
    float lt = lacc * f0;
    float fw[7];
#pragma unroll
    for (int w = 0; w < 7; ++w) {
      fw[w] = exp2f(mlm[w][l15] - ms);
      lt += mll[w][l15] * fw[w];
    }
    const float rl = 1.0f / lt;
    if (qrow < NQ_) {
      f16* xr = X + (size_t)(b * NQ_ + qrow) * 256 + h * 32;
      f16x4 p0, p1;
#pragma unroll
      for (int r = 0; r < 4; ++r) {
        float o0 = O0[r] * f0, o1 = O1[r] * f0;
#pragma unroll
        for (int w = 0; w < 7; ++w) {
          o0 += (float)mO4[w][0][lane][r] * fw[w];
          o1 += (float)mO4[w][1][lane][r] * fw[w];
        }
        p0[r] = (f16)(o0 * rl);
        p1[r] = (f16)(o1 * rl);
      }
      *(f16x4*)(xr + g * 4) = p0;
      *(f16x4*)(xr + 16 + g * 4) = p1;
    }
  }
}

// ---------------------------------------------------------------------------
extern "C" void kernel_launch(void* const* d_in, const int* in_sizes, int n_in,
                              void* d_out, int out_size, void* d_ws, size_t ws_size,
                              hipStream_t stream)
{
  const float* query  = (const float*)d_in[0];
  const float* refpts = (const float*)d_in[1];
  const float* kin    = (const float*)d_in[2];
  const float* vin    = (const float*)d_in[3];
  const int*   mask   = (const int*)d_in[5];
  const float* Wq = (const float*)d_in[6];
  const float* bq = (const float*)d_in[7];
  const float* Wk = (const float*)d_in[8];
  const float* bk = (const float*)d_in[9];
  const float* Wv = (const float*)d_in[10];
  const float* bv = (const float*)d_in[11];
  const float* Wp = (const float*)d_in[12];
  const float* bp = (const float*)d_in[13];
  const float* W1x = (const float*)d_in[14];
  const float* b1x = (const float*)d_in[15];
  const float* W2x = (const float*)d_in[16];
  const float* W1y = (const float*)d_in[17];
  const float* b1y = (const float*)d_in[18];
  const float* W2y = (const float*)d_in[19];

  char* wsb = (char*)d_ws;
  f16*   Qf    = (f16*)(wsb);                 // 1216*256 f16   = 622592 B
  f16*   Kf    = (f16*)(wsb + 622592);        // 4*4096*256 f16 = 8388608 B
  f16*   Vtf   = (f16*)(wsb + 9011200);       // 4*256*4096 f16 = 8388608 B
  float* rpxT  = (float*)(wsb + 17399808);    // 4*8*300*64 f32 = 2457600 B
  float* rpyT  = (float*)(wsb + 19857408);    // 2457600 B
  f16*   X     = (f16*)(wsb + 22315008);      // 1216*256 f16   = 622592 B
  f16*   WT    = (f16*)(wsb + 22937600);      // 4*256*256 f16  = 524288 B
  float* maskf = (float*)(wsb + 23461888);    // 4*4096 f32     = 65536 B

  const float scale = 0.17677669529663687f;  // 32^-0.5

  hipLaunchKernelGGL(prep_wt, dim3(4, 4, 5), dim3(256), 0, stream,
                     Wq, Wk, Wv, Wp, mask, WT, maskf, scale);
  hipLaunchKernelGGL(rpe_kernel, dim3(B_ * NQ_, 2), dim3(256), 0, stream,
                     refpts, W1x, b1x, W2x, W1y, b1y, W2y, rpxT, rpyT);
  hipLaunchKernelGGL(proj_qkv, dim3(4, 256, 3), dim3(256), 0, stream,
                     query, kin, vin, WT, bq, bk, bv, Qf, Kf, Vtf, scale);
  hipLaunchKernelGGL(attn_mfma, dim3(B_ * H_ * QT_), dim3(512), 0, stream,
                     Qf, Kf, Vtf, rpxT, rpyT, maskf, X);
  hipLaunchKernelGGL(gemm_out, dim3(4, 19), dim3(256), 0, stream,
                     X, WT, bp, (float*)d_out);
}